// Round 7
// baseline (284.246 us; speedup 1.0000x reference)
//
#include <hip/hip_runtime.h>
#include <hip/hip_fp16.h>

#define D_MODEL 512
#define D_FF    2048
#define NEXP    8
#define NTOK    4096
#define NPAIR   8192
#define DUMMY   NPAIR
#define LSTRIDE 4224   // 4096 + 128 pad
#define MAXTILES 72
#define WBSTR   (4096 * 512)   // wB rows per expert * D_MODEL

typedef _Float16 half8  __attribute__((ext_vector_type(8)));
typedef _Float16 half2v __attribute__((ext_vector_type(2)));
typedef float    f32x4  __attribute__((ext_vector_type(4)));

__device__ __forceinline__ void gload16(const void* g, void* l) {
  __builtin_amdgcn_global_load_lds(
      (const __attribute__((address_space(1))) unsigned*)g,
      (__attribute__((address_space(3))) unsigned*)l, 16, 0, 0);
}

// counted-vmcnt barrier: drain all but N outstanding VMEM ops, then barrier
#define PIPE_BARRIER(N) do { \
  asm volatile("s_waitcnt vmcnt(" #N ")" ::: "memory"); \
  __builtin_amdgcn_s_barrier(); \
  asm volatile("" ::: "memory"); \
} while (0)
// plain barrier (no vmcnt drain)
#define BAR() do { \
  asm volatile("" ::: "memory"); \
  __builtin_amdgcn_s_barrier(); \
  asm volatile("" ::: "memory"); \
} while (0)

// ---- k_prep: [0,4096) w1/w3 -> wB interleaved; [4096,6144) w2t; rest router -
__global__ __launch_bounds__(256) void k_prep(
    const float* __restrict__ x, const float* __restrict__ rw,
    const float* __restrict__ w1, const float* __restrict__ w3,
    const float* __restrict__ w2, _Float16* __restrict__ wB,
    _Float16* __restrict__ w2t, _Float16* __restrict__ xb,
    int* __restrict__ topE, float* __restrict__ wcomb,
    float* __restrict__ blk, int* __restrict__ ntiles) {
  __shared__ float t[64][65];
  int tid = threadIdx.x;
  if (blockIdx.x < 6144) {
    int bt = blockIdx.x;
    const float* src; int rb, cb, e; bool isw3 = false, isw2 = (bt >= 4096);
    if (!isw2) {
      isw3 = (bt >= 2048);
      src = isw3 ? w3 : w1;
      int tt = bt & 2047; e = tt >> 8; int rem = tt & 255;
      rb = (rem >> 5) * 64; cb = (rem & 31) * 64;          // R=512(d), C=2048(f)
      src += (size_t)e * D_MODEL * D_FF;
    } else {
      int tt = bt - 4096; e = tt >> 8; int rem = tt & 255;
      src = w2;
      rb = (rem >> 3) * 64; cb = (rem & 7) * 64;           // R=2048(f), C=512(d)
      src += (size_t)e * D_FF * D_MODEL;
    }
    int C = isw2 ? D_MODEL : D_FF;
    int tx = tid & 15, ty = tid >> 4;
#pragma unroll
    for (int i = 0; i < 4; i++) {
      float4 v = *(const float4*)(src + (size_t)(rb + ty + i * 16) * C + cb + tx * 4);
      t[ty + i * 16][tx * 4 + 0] = v.x;
      t[ty + i * 16][tx * 4 + 1] = v.y;
      t[ty + i * 16][tx * 4 + 2] = v.z;
      t[ty + i * 16][tx * 4 + 3] = v.w;
    }
    __syncthreads();
    int tx2 = tid & 31, ty2 = tid >> 5;
#pragma unroll
    for (int i = 0; i < 8; i++) {
      int c = ty2 + i * 8;      // local col of src (the new row index)
      int r = tx2 * 2;          // local row of src (contiguous in dst)
      half2v p = {(_Float16)t[r][c], (_Float16)t[r + 1][c]};
      if (!isw2) {
        int f = cb + c;
        int j = ((f >> 5) << 6) + (isw3 ? 32 : 0) + (f & 31);
        *(half2v*)(wB + (size_t)e * WBSTR + (size_t)j * D_MODEL + rb + r) = p;
      } else {
        *(half2v*)(w2t + (size_t)e * D_MODEL * D_FF + (size_t)(cb + c) * D_FF + rb + r) = p;
      }
    }
  } else {
    int bx = blockIdx.x - 6144;
    __shared__ float s_imp[NEXP];
    __shared__ float s_z;
    if (tid < NEXP) s_imp[tid] = 0.f;
    if (tid == 0) s_z = 0.f;
    if (bx == 0 && tid == 0) ntiles[0] = 0;
    __syncthreads();
    int wave = tid >> 6, lane = tid & 63;
    int n = bx * 4 + wave;
    const float* xr = x + (size_t)n * D_MODEL;
    float acc[8] = {0, 0, 0, 0, 0, 0, 0, 0};
    float4 v0 = *(const float4*)(xr + lane * 8);
    float4 v1 = *(const float4*)(xr + lane * 8 + 4);
    float xs[8] = {v0.x, v0.y, v0.z, v0.w, v1.x, v1.y, v1.z, v1.w};
    half8 hx = {(_Float16)xs[0], (_Float16)xs[1], (_Float16)xs[2], (_Float16)xs[3],
                (_Float16)xs[4], (_Float16)xs[5], (_Float16)xs[6], (_Float16)xs[7]};
    *(half8*)(xb + (size_t)n * D_MODEL + lane * 8) = hx;
#pragma unroll
    for (int j = 0; j < 8; j++) {
      const float4* w4 = (const float4*)(rw + (size_t)(lane * 8 + j) * NEXP);
      float4 wa = w4[0], wb = w4[1];
      acc[0] += xs[j] * wa.x; acc[1] += xs[j] * wa.y;
      acc[2] += xs[j] * wa.z; acc[3] += xs[j] * wa.w;
      acc[4] += xs[j] * wb.x; acc[5] += xs[j] * wb.y;
      acc[6] += xs[j] * wb.z; acc[7] += xs[j] * wb.w;
    }
#pragma unroll
    for (int off = 32; off >= 1; off >>= 1) {
#pragma unroll
      for (int e = 0; e < 8; e++) acc[e] += __shfl_xor(acc[e], off);
    }
    if (lane == 0) {
      float z = 0.f;
#pragma unroll
      for (int e = 0; e < 8; e++) z += acc[e] * acc[e];
      float m = acc[0];
#pragma unroll
      for (int e = 1; e < 8; e++) m = fmaxf(m, acc[e]);
      float p[8], s = 0.f;
#pragma unroll
      for (int e = 0; e < 8; e++) { p[e] = expf(acc[e] - m); s += p[e]; }
      float inv = 1.f / s;
#pragma unroll
      for (int e = 0; e < 8; e++) p[e] *= inv;
      int e0 = 0; float p0 = p[0];
#pragma unroll
      for (int e = 1; e < 8; e++) if (p[e] > p0) { p0 = p[e]; e0 = e; }
      int e1 = -1; float p1 = -1.f;
#pragma unroll
      for (int e = 0; e < 8; e++) if (e != e0 && p[e] > p1) { p1 = p[e]; e1 = e; }
      float wsum = p0 + p1;
      topE[n] = e0 | (e1 << 4);
      wcomb[2 * n] = p0 / wsum;
      wcomb[2 * n + 1] = p1 / wsum;
#pragma unroll
      for (int e = 0; e < 8; e++) atomicAdd(&s_imp[e], p[e]);
      atomicAdd(&s_z, z);
    }
    __syncthreads();
    if (tid < 8) blk[bx * 9 + tid] = s_imp[tid];
    if (tid == 8) blk[bx * 9 + 8] = s_z;
  }
}

// ------- scatter: 8 blocks (1/expert): build list, pad, tile table, load -----
__global__ __launch_bounds__(1024) void k_scatter(
    const int* __restrict__ topE, int* __restrict__ lists,
    int* __restrict__ tiletab, int* __restrict__ ntiles,
    int* __restrict__ loadc_g) {
  int e = blockIdx.x;
  __shared__ int wcount[16];
  __shared__ int lcw[16];
  __shared__ int sbase;
  __shared__ int stot;
  int tid = threadIdx.x, lane = tid & 63, wv = tid >> 6;
  if (lane == 0) lcw[wv] = 0;
  int total = 0;
  for (int c = 0; c < 8; c++) {
    int idx = c * 1024 + tid;
    int te = topE[idx >> 1];
    int ee = (idx & 1) ? ((te >> 4) & 15) : (te & 15);
    bool mine = (ee == e);
    unsigned long long bal = __ballot(mine);
    unsigned long long balL = __ballot(mine && !(idx & 1));  // convergent
    int rank = __popcll(bal & ((1ull << lane) - 1ull));
    if (lane == 0) {
      wcount[wv] = __popcll(bal);
      lcw[wv] += __popcll(balL);
    }
    __syncthreads();
    int pre = total;
    for (int w2 = 0; w2 < wv; w2++) pre += wcount[w2];
    if (mine) lists[e * LSTRIDE + pre + rank] = idx;
    int t16 = 0;
#pragma unroll
    for (int w2 = 0; w2 < 16; w2++) t16 += wcount[w2];
    __syncthreads();
    total += t16;
  }
  int tiles = (total + 127) >> 7;
  if (tid == 0) {
    int lc = 0;
#pragma unroll
    for (int w2 = 0; w2 < 16; w2++) lc += lcw[w2];
    loadc_g[e] = lc;
    sbase = atomicAdd(ntiles, tiles);
    stot = total;
  }
  __syncthreads();
  if (tid < tiles) tiletab[sbase + tid] = e | (tid << 8);
  if (tid < 128) {
    int p = stot + tid;
    if (p < tiles * 128) lists[e * LSTRIDE + p] = DUMMY;
  }
}

// -------- gemm1: 128x256 tile, BK=64, 8 waves, 3-buf phase-split pipeline ----
__global__ __launch_bounds__(512) void k_gemm1(
    const _Float16* __restrict__ xb, const _Float16* __restrict__ wB,
    _Float16* __restrict__ h, const int* __restrict__ lists,
    const int* __restrict__ tiletab, const int* __restrict__ ntiles) {
  int ti = blockIdx.y;
  if (ti >= ntiles[0]) return;
  int ent = tiletab[ti];
  int e = ent & 15, mt = ent >> 8, nt = blockIdx.x;
  __shared__ __align__(16) _Float16 Asl[3][128 * 64];
  __shared__ __align__(16) _Float16 Bsl[3][256 * 64];
  __shared__ int toks[128];
  int tid = threadIdx.x, lane = tid & 63, w = tid >> 6;
  if (tid < 128) toks[tid] = lists[e * LSTRIDE + mt * 128 + tid];
  __syncthreads();
  const _Float16* wBe = wB + (size_t)e * WBSTR;
  int l3 = lane >> 3, l7 = lane & 7;
  const _Float16* aSrc[2];
  const _Float16* bSrc[4];
#pragma unroll
  for (int g = 0; g < 2; g++) {
    int r = w * 16 + g * 8 + l3;
    aSrc[g] = xb + (size_t)(toks[r] >> 1) * D_MODEL + ((l7 ^ (r & 7)) << 3);
  }
#pragma unroll
  for (int g = 0; g < 4; g++) {
    int r = w * 32 + g * 8 + l3;
    bSrc[g] = wBe + (size_t)(nt * 256 + r) * D_MODEL + ((l7 ^ (r & 7)) << 3);
  }
  int wm = w >> 2, wn = w & 3;
  int la = lane & 15, lh = lane >> 4;
  int aoff[4][2], boff[4][2];
#pragma unroll
  for (int mf = 0; mf < 4; mf++)
#pragma unroll
    for (int kh = 0; kh < 2; kh++) {
      int r = wm * 64 + mf * 16 + la;
      aoff[mf][kh] = r * 64 + (((kh * 4 + lh) ^ (r & 7)) << 3);
      int rb = wn * 64 + mf * 16 + la;
      boff[mf][kh] = rb * 64 + (((kh * 4 + lh) ^ (rb & 7)) << 3);
    }
  f32x4 acc[4][4] = {};
#define G1_SA(T, BUF) do { _Pragma("unroll") \
  for (int g = 0; g < 2; g++) gload16(aSrc[g] + (T) * 64, &Asl[BUF][(w * 16 + g * 8) * 64]); } while (0)
#define G1_SB(T, BUF) do { _Pragma("unroll") \
  for (int g = 0; g < 4; g++) gload16(bSrc[g] + (T) * 64, &Bsl[BUF][(w * 32 + g * 8) * 64]); } while (0)
  // prologue: 2 tiles in flight (12 loads), drain tile 0 only
  G1_SA(0, 0); G1_SB(0, 0);
  G1_SA(1, 1); G1_SB(1, 1);
  PIPE_BARRIER(6);
#pragma unroll
  for (int t = 0; t < 8; t++) {
    const int cur = t % 3, nxt = (t + 2) % 3;
    // ---- phase kh0: ds_read, issue A-stage(t+2), barrier, MFMA ----
    {
      half8 af[4], bf[4];
#pragma unroll
      for (int nf = 0; nf < 4; nf++) bf[nf] = *(const half8*)(&Bsl[cur][boff[nf][0]]);
#pragma unroll
      for (int mf = 0; mf < 4; mf++) af[mf] = *(const half8*)(&Asl[cur][aoff[mf][0]]);
      if (t < 6) G1_SA(t + 2, nxt);
      BAR();
      __builtin_amdgcn_s_setprio(1);
#pragma unroll
      for (int mf = 0; mf < 4; mf++)
#pragma unroll
        for (int nf = 0; nf < 4; nf++)
          acc[mf][nf] = __builtin_amdgcn_mfma_f32_16x16x32_f16(af[mf], bf[nf], acc[mf][nf], 0, 0, 0);
      __builtin_amdgcn_s_setprio(0);
      BAR();
    }
    // ---- phase kh1: ds_read, issue B-stage(t+2), counted vmcnt, MFMA ----
    {
      half8 af[4], bf[4];
#pragma unroll
      for (int nf = 0; nf < 4; nf++) bf[nf] = *(const half8*)(&Bsl[cur][boff[nf][1]]);
#pragma unroll
      for (int mf = 0; mf < 4; mf++) af[mf] = *(const half8*)(&Asl[cur][aoff[mf][1]]);
      if (t < 6) G1_SB(t + 2, nxt);
      if (t < 6)      PIPE_BARRIER(6);   // drain stage(t+1); stage(t+2) stays in flight
      else if (t == 6) PIPE_BARRIER(0);  // tail: drain stage(7)
      else            BAR();
      __builtin_amdgcn_s_setprio(1);
#pragma unroll
      for (int mf = 0; mf < 4; mf++)
#pragma unroll
        for (int nf = 0; nf < 4; nf++)
          acc[mf][nf] = __builtin_amdgcn_mfma_f32_16x16x32_f16(af[mf], bf[nf], acc[mf][nf], 0, 0, 0);
      __builtin_amdgcn_s_setprio(0);
      if (t < 7) BAR();
    }
  }
#undef G1_SA
#undef G1_SB
  // epilogue: silu(g)*u ; acc[.][nf] pairs with acc[.][nf+2] (same h-col)
  int fbase = (nt * 4 + wn) * 32;
#pragma unroll
  for (int mf = 0; mf < 4; mf++) {
    int mb = wm * 64 + mf * 16 + (lh << 2);
#pragma unroll
    for (int q = 0; q < 4; q++) {
      int m = mb + q;
      int pair = toks[m];
      _Float16* hrow = h + (size_t)pair * D_FF + fbase;
#pragma unroll
      for (int nf = 0; nf < 2; nf++) {
        float g = acc[mf][nf][q], u = acc[mf][nf + 2][q];
        hrow[nf * 16 + la] = (_Float16)((g / (1.f + __expf(-g))) * u);
      }
    }
  }
}

// -------- gemm2: 128x256 tile, BK=64, split-K=2, 3-buf phase-split pipeline --
__global__ __launch_bounds__(512) void k_gemm2(
    const _Float16* __restrict__ h, const _Float16* __restrict__ w2t,
    float* __restrict__ po2, const int* __restrict__ lists,
    const int* __restrict__ tiletab, const int* __restrict__ ntiles,
    const float* __restrict__ wcomb) {
  int ti = blockIdx.y;
  if (ti >= ntiles[0]) return;
  int ent = tiletab[ti];
  int e = ent & 15, mt = ent >> 8;
  int nt = blockIdx.x & 1, ks = blockIdx.x >> 1;
  __shared__ __align__(16) _Float16 Asl[3][128 * 64];
  __shared__ __align__(16) _Float16 Bsl[3][256 * 64];
  __shared__ int toks[128];
  __shared__ float wcs[128];
  int tid = threadIdx.x, lane = tid & 63, w = tid >> 6;
  if (tid < 128) {
    int p = lists[e * LSTRIDE + mt * 128 + tid];
    toks[tid] = p;
    wcs[tid] = (p < NPAIR) ? wcomb[p] : 0.f;
  }
  __syncthreads();
  const _Float16* w2e = w2t + (size_t)e * D_MODEL * D_FF;
  const int kb = ks * 1024;
  int l3 = lane >> 3, l7 = lane & 7;
  const _Float16* aSrc[2];
  const _Float16* bSrc[4];
#pragma unroll
  for (int g = 0; g < 2; g++) {
    int r = w * 16 + g * 8 + l3;
    aSrc[g] = h + (size_t)toks[r] * D_FF + kb + ((l7 ^ (r & 7)) << 3);
  }
#pragma unroll
  for (int g = 0; g < 4; g++) {
    int r = w * 32 + g * 8 + l3;
    bSrc[g] = w2e + (size_t)(nt * 256 + r) * D_FF + kb + ((l7 ^ (r & 7)) << 3);
  }
  int wm = w >> 2, wn = w & 3;
  int la = lane & 15, lh = lane >> 4;
  int aoff[4][2], boff[4][2];
#pragma unroll
  for (int mf = 0; mf < 4; mf++)
#pragma unroll
    for (int kh = 0; kh < 2; kh++) {
      int r = wm * 64 + mf * 16 + la;
      aoff[mf][kh] = r * 64 + (((kh * 4 + lh) ^ (r & 7)) << 3);
      int rb = wn * 64 + mf * 16 + la;
      boff[mf][kh] = rb * 64 + (((kh * 4 + lh) ^ (rb & 7)) << 3);
    }
  f32x4 acc[4][4] = {};
#define G2_SA(T, BUF) do { _Pragma("unroll") \
  for (int g = 0; g < 2; g++) gload16(aSrc[g] + (T) * 64, &Asl[BUF][(w * 16 + g * 8) * 64]); } while (0)
#define G2_SB(T, BUF) do { _Pragma("unroll") \
  for (int g = 0; g < 4; g++) gload16(bSrc[g] + (T) * 64, &Bsl[BUF][(w * 32 + g * 8) * 64]); } while (0)
  G2_SA(0, 0); G2_SB(0, 0);
  G2_SA(1, 1); G2_SB(1, 1);
  PIPE_BARRIER(6);
#pragma unroll
  for (int t = 0; t < 16; t++) {
    const int cur = t % 3, nxt = (t + 2) % 3;
    {
      half8 af[4], bf[4];
#pragma unroll
      for (int nf = 0; nf < 4; nf++) bf[nf] = *(const half8*)(&Bsl[cur][boff[nf][0]]);
#pragma unroll
      for (int mf = 0; mf < 4; mf++) af[mf] = *(const half8*)(&Asl[cur][aoff[mf][0]]);
      if (t < 14) G2_SA(t + 2, nxt);
      BAR();
      __builtin_amdgcn_s_setprio(1);
#pragma unroll
      for (int mf = 0; mf < 4; mf++)
#pragma unroll
        for (int nf = 0; nf < 4; nf++)
          acc[mf][nf] = __builtin_amdgcn_mfma_f32_16x16x32_f16(af[mf], bf[nf], acc[mf][nf], 0, 0, 0);
      __builtin_amdgcn_s_setprio(0);
      BAR();
    }
    {
      half8 af[4], bf[4];
#pragma unroll
      for (int nf = 0; nf < 4; nf++) bf[nf] = *(const half8*)(&Bsl[cur][boff[nf][1]]);
#pragma unroll
      for (int mf = 0; mf < 4; mf++) af[mf] = *(const half8*)(&Asl[cur][aoff[mf][1]]);
      if (t < 14) G2_SB(t + 2, nxt);
      if (t < 14)      PIPE_BARRIER(6);
      else if (t == 14) PIPE_BARRIER(0);
      else             BAR();
      __builtin_amdgcn_s_setprio(1);
#pragma unroll
      for (int mf = 0; mf < 4; mf++)
#pragma unroll
        for (int nf = 0; nf < 4; nf++)
          acc[mf][nf] = __builtin_amdgcn_mfma_f32_16x16x32_f16(af[mf], bf[nf], acc[mf][nf], 0, 0, 0);
      __builtin_amdgcn_s_setprio(0);
      if (t < 15) BAR();
    }
  }
#undef G2_SA
#undef G2_SB
  int dbase = nt * 256 + wn * 64;
#pragma unroll
  for (int mf = 0; mf < 4; mf++) {
    int mb = wm * 64 + mf * 16 + (lh << 2);
#pragma unroll
    for (int q = 0; q < 4; q++) {
      int m = mb + q;
      int pair = toks[m];
      if (pair < NPAIR) {
        float wv = wcs[m];
        float* orow = po2 + ((size_t)ks * NPAIR + pair) * D_MODEL + dbase;
#pragma unroll
        for (int nf = 0; nf < 4; nf++)
          orow[nf * 16 + la] = acc[mf][nf][q] * wv;
      }
    }
  }
}

// ------- combine: out[n] = sum over {split}x{2 pairs}; block 0 also losses ---
__global__ void k_combine(const float* __restrict__ po2, float* __restrict__ out,
                          const float* __restrict__ blk,
                          const int* __restrict__ loadc_g) {
  int gid = blockIdx.x * blockDim.x + threadIdx.x;
  int r = gid >> 7;
  int c = (gid & 127) * 4;
  const float4 a0 = *(const float4*)(po2 + (size_t)(2 * r) * D_MODEL + c);
  const float4 a1 = *(const float4*)(po2 + (size_t)(2 * r + 1) * D_MODEL + c);
  const float4 b0 = *(const float4*)(po2 + (size_t)(NPAIR + 2 * r) * D_MODEL + c);
  const float4 b1 = *(const float4*)(po2 + (size_t)(NPAIR + 2 * r + 1) * D_MODEL + c);
  float4 o{a0.x + a1.x + b0.x + b1.x, a0.y + a1.y + b0.y + b1.y,
           a0.z + a1.z + b0.z + b1.z, a0.w + a1.w + b0.w + b1.w};
  *(float4*)(out + (size_t)r * D_MODEL + c) = o;
  if (blockIdx.x == 0) {
    __shared__ float fin[9];
    int lane = threadIdx.x & 63, wv = threadIdx.x >> 6;
    for (int j = wv; j < 9; j += 4) {
      float s = 0.f;
      for (int b = lane; b < 1024; b += 64) s += blk[b * 9 + j];
#pragma unroll
      for (int off = 32; off >= 1; off >>= 1) s += __shfl_xor(s, off);
      if (lane == 0) fin[j] = s;
    }
    __syncthreads();
    if (threadIdx.x == 0) {
      float a = 0.f;
#pragma unroll
      for (int e = 0; e < 8; e++)
        a += (fin[e] * (1.f / 4096.f)) * ((float)loadc_g[e] * (1.f / 4096.f));
      out[NTOK * D_MODEL] = 8.f * a * 0.01f;
      out[NTOK * D_MODEL + 1] = fin[8] * (1.f / (4096.f * 8.f)) * 1e-4f;
    }
  }
}

extern "C" void kernel_launch(void* const* d_in, const int* in_sizes, int n_in,
                              void* d_out, int out_size, void* d_ws, size_t ws_size,
                              hipStream_t stream) {
  const float* x = (const float*)d_in[0];
  const float* rw = (const float*)d_in[1];
  const float* w1 = (const float*)d_in[2];
  const float* w2 = (const float*)d_in[3];
  const float* w3 = (const float*)d_in[4];
  float* out = (float*)d_out;

  char* ws = (char*)d_ws;
  size_t o = 0;
  _Float16* wB = (_Float16*)(ws + o); o += (size_t)NEXP * WBSTR * 2;           // 33.55 MB
  _Float16* w2t = (_Float16*)(ws + o); o += (size_t)NEXP * D_MODEL * D_FF * 2; // 16.8 MB
  _Float16* xb = (_Float16*)(ws + o); o += (size_t)(NTOK + 1) * D_MODEL * 2;
  _Float16* hbuf = (_Float16*)(ws + o); o += (size_t)(NPAIR + 1) * D_FF * 2;
  int* lists = (int*)(ws + o); o += (size_t)NEXP * LSTRIDE * 4;
  float* wcomb = (float*)(ws + o); o += (size_t)NPAIR * 4;
  int* topE = (int*)(ws + o); o += (size_t)NTOK * 4;
  float* blk = (float*)(ws + o); o += (size_t)1024 * 9 * 4;
  int* tiletab = (int*)(ws + o); o += MAXTILES * 4;
  int* ntiles = (int*)(ws + o); o += 16;
  int* loadc_g = (int*)(ws + o); o += 64;
  // po2 (2 splits x 8192 x 512 f32 = 33,554,432 B) aliases wB exactly
  // (wB dead after gemm1; gemm2/combine run later)
  float* po2 = (float*)ws;
  if (ws_size < o) return;  // workspace too small — refuse to corrupt

  k_prep<<<7168, 256, 0, stream>>>(x, rw, w1, w3, w2, wB, w2t, xb, topE,
                                   wcomb, blk, ntiles);
  k_scatter<<<NEXP, 1024, 0, stream>>>(topE, lists, tiletab, ntiles, loadc_g);
  k_gemm1<<<dim3(16, MAXTILES), 512, 0, stream>>>(xb, wB, hbuf, lists, tiletab, ntiles);
  k_gemm2<<<dim3(4, MAXTILES), 512, 0, stream>>>(hbuf, w2t, po2, lists, tiletab, ntiles, wcomb);
  k_combine<<<(NTOK * D_MODEL / 4 + 255) / 256, 256, 0, stream>>>(po2, out, blk, loadc_g);
}